// Round 1
// baseline (390.994 us; speedup 1.0000x reference)
//
#include <hip/hip_runtime.h>
#include <math.h>

#define BB 4
#define TT 1024
#define FIN 256
#define DD 128
#define CL 16              // chunk length
#define NC 64              // chunks = TT/CL
#define ROWS (BB*TT)       // 4096

// ---------------------------------------------------------------------------
// Kernel 1: LayerNorm + 4 GEMMs (K,Q with phi=elu+1; V plain; XS = xn@Ws^T+bs)
// grid 512 x 256 threads, 8 rows/block.  (unchanged)
// ---------------------------------------------------------------------------
__global__ __launch_bounds__(256) void k_ln_qkv(
    const float* __restrict__ x, const float* __restrict__ gamma, const float* __restrict__ beta,
    const float* __restrict__ Wk, const float* __restrict__ Wq, const float* __restrict__ Wv,
    const float* __restrict__ Ws, const float* __restrict__ bs,
    float* __restrict__ Kp, float* __restrict__ Qp, float* __restrict__ Vp, float* __restrict__ XSp)
{
    __shared__ float xt[8][FIN];
    const int tid  = threadIdx.x;
    const int row0 = blockIdx.x * 8;

    {
        const int r = tid >> 5, l = tid & 31;
        const float* xr = x + (size_t)(row0 + r) * FIN + l * 8;
        float v[8];
        #pragma unroll
        for (int k = 0; k < 8; ++k) v[k] = xr[k];
        float s = 0.f, sq = 0.f;
        #pragma unroll
        for (int k = 0; k < 8; ++k) { s += v[k]; sq += v[k] * v[k]; }
        #pragma unroll
        for (int m = 16; m >= 1; m >>= 1) {
            s  += __shfl_xor(s,  m, 64);
            sq += __shfl_xor(sq, m, 64);
        }
        const float mu  = s * (1.0f / FIN);
        const float var = sq * (1.0f / FIN) - mu * mu;
        const float rs  = rsqrtf(var + 1e-5f);
        #pragma unroll
        for (int k = 0; k < 8; ++k) {
            const int f = l * 8 + k;
            xt[r][f] = (v[k] - mu) * rs * gamma[f] + beta[f];
        }
    }
    __syncthreads();

    const int m0 = tid >> 7;            // 0 -> K, 1 -> Q
    const int d  = tid & 127;
    const int m1 = (tid + 256) >> 7;    // 2 -> V, 3 -> XS
    const float* W0 = (m0 == 0 ? Wk : Wq) + (size_t)d * FIN;
    const float* W1r = (m1 == 2 ? Wv : Ws) + (size_t)d * FIN;

    float acc0[8], acc1[8];
    #pragma unroll
    for (int r = 0; r < 8; ++r) { acc0[r] = 0.f; acc1[r] = 0.f; }

    for (int k4 = 0; k4 < FIN / 4; ++k4) {
        const float4 w0 = ((const float4*)W0)[k4];
        const float4 w1 = ((const float4*)W1r)[k4];
        #pragma unroll
        for (int r = 0; r < 8; ++r) {
            const float4 xv = ((const float4*)xt[r])[k4];
            acc0[r] += w0.x * xv.x + w0.y * xv.y + w0.z * xv.z + w0.w * xv.w;
            acc1[r] += w1.x * xv.x + w1.y * xv.y + w1.z * xv.z + w1.w * xv.w;
        }
    }

    float* dst0 = (m0 == 0 ? Kp : Qp);
    float* dst1 = (m1 == 2 ? Vp : XSp);
    const float bsv = (m1 == 3) ? bs[d] : 0.f;
    #pragma unroll
    for (int r = 0; r < 8; ++r) {
        float a = acc0[r];
        a = (a > 0.f) ? (a + 1.f) : expf(a);          // phi = elu+1
        dst0[(size_t)(row0 + r) * DD + d] = a;
        dst1[(size_t)(row0 + r) * DD + d] = acc1[r] + bsv;
    }
}

// ---------------------------------------------------------------------------
// Kernel 2: per-chunk sums  sumKV[b,c,i,j] = sum_t K[t,i]V[t,j], sumK[b,c,i]
// grid 256 (b*c) x 256 threads  (unchanged)
// ---------------------------------------------------------------------------
__global__ __launch_bounds__(256) void k_chunksum(
    const float* __restrict__ Kp, const float* __restrict__ Vp,
    float* __restrict__ SKV, float* __restrict__ SK)
{
    __shared__ float Kb[CL][DD];
    __shared__ float Vb[CL][DD];
    const int tid = threadIdx.x;
    const int c = blockIdx.x & (NC - 1);
    const int b = blockIdx.x >> 6;
    const size_t base = (size_t)(b * TT + c * CL) * DD;

    #pragma unroll
    for (int q = 0; q < 2; ++q) {
        const int fi = q * 256 + tid;
        ((float4*)&Kb[0][0])[fi] = ((const float4*)(Kp + base))[fi];
        ((float4*)&Vb[0][0])[fi] = ((const float4*)(Vp + base))[fi];
    }
    __syncthreads();

    const int j = tid & 127, hi = tid >> 7;
    float acc[64];
    #pragma unroll
    for (int w = 0; w < 64; ++w) acc[w] = 0.f;

    for (int t = 0; t < CL; ++t) {
        const float vj = Vb[t][j];
        #pragma unroll
        for (int w4 = 0; w4 < 16; ++w4) {
            const float4 kf = *(const float4*)&Kb[t][hi * 64 + w4 * 4];
            acc[w4 * 4 + 0] += kf.x * vj;
            acc[w4 * 4 + 1] += kf.y * vj;
            acc[w4 * 4 + 2] += kf.z * vj;
            acc[w4 * 4 + 3] += kf.w * vj;
        }
    }

    float* out = SKV + (size_t)(b * NC + c) * DD * DD;
    #pragma unroll
    for (int w = 0; w < 64; ++w) {
        const int i = hi * 64 + w;
        out[(size_t)i * DD + j] = acc[w];
    }
    if (tid < DD) {
        float s = 0.f;
        #pragma unroll
        for (int t = 0; t < CL; ++t) s += Kb[t][tid];
        SK[(size_t)(b * NC + c) * DD + tid] = s;
    }
}

// ---------------------------------------------------------------------------
// Kernel 3: prefix over chunks -> writes chunk-END slices of S and Z outputs.
// Loads batched 8-wide for ILP (was a serial 64-deep HBM-latency chain).
// grid 256 x 256 (one thread per (b,i,j))
// ---------------------------------------------------------------------------
__global__ __launch_bounds__(256) void k_prefix(
    const float* __restrict__ SKV, const float* __restrict__ SK,
    const float* __restrict__ S0, const float* __restrict__ Z0,
    float* __restrict__ Sout, float* __restrict__ Zout)
{
    const int gid = blockIdx.x * 256 + threadIdx.x;   // 0..65535
    const int b = gid >> 14, e = gid & 16383;
    float acc = S0[(size_t)b * 16384 + e];
    const float* p = SKV + (size_t)b * NC * 16384 + e;
    float* so = Sout + (size_t)b * TT * 16384 + (size_t)(CL - 1) * 16384 + e;
    for (int c0 = 0; c0 < NC; c0 += 8) {
        float v[8];
        #pragma unroll
        for (int q = 0; q < 8; ++q) v[q] = p[(size_t)(c0 + q) * 16384];
        #pragma unroll
        for (int q = 0; q < 8; ++q) { acc += v[q]; so[(size_t)(c0 + q) * CL * 16384] = acc; }
    }
    if (gid < BB * DD) {
        const int b2 = gid >> 7, i = gid & 127;
        float z = Z0[b2 * DD + i];
        const float* pk = SK + (size_t)b2 * NC * DD + i;
        float* zo = Zout + ((size_t)b2 * TT + CL - 1) * DD + i;
        for (int c0 = 0; c0 < NC; c0 += 8) {
            float v[8];
            #pragma unroll
            for (int q = 0; q < 8; ++q) v[q] = pk[(size_t)(c0 + q) * DD];
            #pragma unroll
            for (int q = 0; q < 8; ++q) { z += v[q]; zo[(size_t)(c0 + q) * CL * DD] = z; }
        }
    }
}

// ---------------------------------------------------------------------------
// Kernel 4: fused NUM/den/MLP via chunked-linear-attention identity:
//   A = mask(Q K^T)  (16x16, inclusive causal)
//   num[t] = Q[t] @ S_start + sum_u A[t,u] V[u]
//   den[t] = Q[t] . Z_start + rowsum(A[t])
// Then h0 = num/den, 2-layer relu MLP, + XS residual. Also writes Z rows t<15.
// grid 256 (b*c) x 256 threads.  Launched BEFORE the S-writer so the 16.8 MB
// of chunk-end rows are still L3-hot from k_prefix.
// ---------------------------------------------------------------------------
__global__ __launch_bounds__(256) void k_num_mlp(
    const float* __restrict__ Qp, const float* __restrict__ Kp, const float* __restrict__ Vp,
    const float* __restrict__ XSp, const float* __restrict__ S0, const float* __restrict__ Z0,
    const float* __restrict__ W1, const float* __restrict__ b1,
    const float* __restrict__ W2, const float* __restrict__ b2,
    const float* Sce,            // = Sout (reads chunk-end rows only)
    float* Zout,                 // reads chunk-end rows, writes rows t<CL-1
    float* __restrict__ Oout)
{
    __shared__ float Qb[CL][132];   // +4 pad keeps 16B alignment, breaks bank aliasing
    __shared__ float Kb[CL][132];
    __shared__ float Vb[CL][DD];
    __shared__ float Ab[CL][CL];
    __shared__ float zs[DD];
    __shared__ float red[2][CL][DD];
    __shared__ float h0[CL][DD];
    __shared__ float h1[CL][DD];
    __shared__ float parr[CL][256];
    __shared__ float denl[CL];

    const int tid = threadIdx.x;
    const int c = blockIdx.x & (NC - 1);
    const int b = blockIdx.x >> 6;
    const size_t rbase = (size_t)(b * TT + c * CL);
    const int d = tid & 127, s = tid >> 7;

    // preload MLP weights early (hide HBM/L2 latency under staging + phase A)
    float4 w1r[16], w2r[16];
    #pragma unroll
    for (int k4 = 0; k4 < 16; ++k4) {
        w1r[k4] = *(const float4*)(W1 + (size_t)d * DD + s * 64 + k4 * 4);
        w2r[k4] = *(const float4*)(W2 + (size_t)d * DD + s * 64 + k4 * 4);
    }

    // stage Q, K (padded rows), V
    #pragma unroll
    for (int q = 0; q < 2; ++q) {
        const int idx = q * 256 + tid;
        const int t = idx >> 5, jq = idx & 31;
        *(float4*)&Qb[t][jq * 4] = *(const float4*)(Qp + (rbase + t) * DD + jq * 4);
        *(float4*)&Kb[t][jq * 4] = *(const float4*)(Kp + (rbase + t) * DD + jq * 4);
        ((float4*)&Vb[0][0])[idx] = ((const float4*)(Vp + rbase * DD))[idx];
    }
    if (tid < DD)
        zs[tid] = (c == 0) ? Z0[b * DD + tid] : Zout[(rbase - 1) * DD + tid];
    __syncthreads();

    // ---- Phase A: A = mask(QK^T), den = Q.Zstart + rowsum(A) ----
    {
        const int t = tid >> 4, u = tid & 15;
        float a = 0.f;
        #pragma unroll
        for (int k4 = 0; k4 < 32; ++k4) {
            const float4 q4 = *(const float4*)&Qb[t][k4 * 4];
            const float4 kv = *(const float4*)&Kb[u][k4 * 4];
            a += q4.x * kv.x + q4.y * kv.y + q4.z * kv.z + q4.w * kv.w;
        }
        const float am = (u <= t) ? a : 0.f;      // inclusive causal mask
        Ab[t][u] = am;
        float dz = 0.f;
        #pragma unroll
        for (int kk = 0; kk < 8; ++kk) dz += Qb[t][u * 8 + kk] * zs[u * 8 + kk];
        float r = am + dz;
        #pragma unroll
        for (int m = 1; m <= 8; m <<= 1) r += __shfl_xor(r, m, 64);
        if (u == 0) denl[t] = r + 1e-5f;
    }

    // ---- Z rows t < CL-1 (chunk-end row already written by k_prefix) ----
    if (tid < DD) {
        float z = zs[tid];
        for (int t = 0; t < CL - 1; ++t) {
            z += Kb[t][tid];
            Zout[(rbase + t) * DD + tid] = z;
        }
    }
    __syncthreads();

    // ---- NUM part1: Q @ S_start   (k split across s halves) ----
    {
        float nt[CL];
        #pragma unroll
        for (int t = 0; t < CL; ++t) nt[t] = 0.f;
        const float* sst = (c == 0) ? (S0 + (size_t)b * 16384)
                                    : (Sce + (rbase - 1) * 16384);
        #pragma unroll 4
        for (int k4 = s * 16; k4 < s * 16 + 16; ++k4) {
            const int k = k4 * 4;
            const float sv0 = sst[(size_t)(k + 0) * DD + d];
            const float sv1 = sst[(size_t)(k + 1) * DD + d];
            const float sv2 = sst[(size_t)(k + 2) * DD + d];
            const float sv3 = sst[(size_t)(k + 3) * DD + d];
            #pragma unroll
            for (int t = 0; t < CL; ++t) {
                const float4 q4 = *(const float4*)&Qb[t][k];
                nt[t] += q4.x * sv0 + q4.y * sv1 + q4.z * sv2 + q4.w * sv3;
            }
        }
        #pragma unroll
        for (int t = 0; t < CL; ++t) red[s][t][d] = nt[t];
    }
    __syncthreads();

    // ---- part2: num += A@V, h0 = num/den  (t split across s halves) ----
    #pragma unroll
    for (int tl = 0; tl < 8; ++tl) {
        const int t = s * 8 + tl;
        float num = red[0][t][d] + red[1][t][d];
        #pragma unroll
        for (int u = 0; u < CL; ++u) num += Ab[t][u] * Vb[u][d];
        h0[t][d] = num / denl[t];
    }
    __syncthreads();

    // ---- MLP layer 1 ----
    #pragma unroll
    for (int r = 0; r < 16; ++r) {
        float pp = 0.f;
        #pragma unroll
        for (int k4 = 0; k4 < 16; ++k4) {
            const float4 xv = *(const float4*)&h0[r][s * 64 + k4 * 4];
            pp += w1r[k4].x * xv.x + w1r[k4].y * xv.y + w1r[k4].z * xv.z + w1r[k4].w * xv.w;
        }
        parr[r][tid] = pp;
    }
    __syncthreads();
    #pragma unroll
    for (int q = 0; q < 8; ++q) {
        const int f = q * 256 + tid;
        const int r = f >> 7, dd2 = f & 127;
        h1[r][dd2] = fmaxf(parr[r][dd2] + parr[r][dd2 + 128] + b1[dd2], 0.f);
    }
    __syncthreads();

    // ---- MLP layer 2 + residual ----
    #pragma unroll
    for (int r = 0; r < 16; ++r) {
        float pp = 0.f;
        #pragma unroll
        for (int k4 = 0; k4 < 16; ++k4) {
            const float4 xv = *(const float4*)&h1[r][s * 64 + k4 * 4];
            pp += w2r[k4].x * xv.x + w2r[k4].y * xv.y + w2r[k4].z * xv.z + w2r[k4].w * xv.w;
        }
        parr[r][tid] = pp;
    }
    __syncthreads();
    #pragma unroll
    for (int q = 0; q < 8; ++q) {
        const int f = q * 256 + tid;
        const int r = f >> 7, dd2 = f & 127;
        const float hv = fmaxf(parr[r][dd2] + parr[r][dd2 + 128] + b2[dd2], 0.f);
        Oout[rbase * DD + f] = hv + XSp[rbase * DD + f];
    }
}

// ---------------------------------------------------------------------------
// Kernel 5: pure S-row writer. block = (b, chunk, i-half). State 64x128 in
// registers (32 floats/thread). NO barriers / NO vmcnt drains in the t-loop;
// each wave's store is one fully-coalesced 1 KB transaction.
// Skips the t=CL-1 update (chunk-end rows come from k_prefix).
// grid 512 x 256 threads
// ---------------------------------------------------------------------------
__global__ __launch_bounds__(256) void k_scan(
    const float* __restrict__ Kp, const float* __restrict__ Vp,
    const float* __restrict__ S0, float* Sout)
{
    __shared__ float Kb[CL][64];
    __shared__ float Vb[CL][DD];
    const int tid = threadIdx.x;
    const int ih  = blockIdx.x & 1;
    const int c   = (blockIdx.x >> 1) & (NC - 1);
    const int b   = blockIdx.x >> 7;
    const int i0  = ih * 64;
    const size_t rbase = (size_t)(b * TT + c * CL);

    {   // stage V (full) + K slice for this i-half
        const float4* Vsrc = (const float4*)(Vp + rbase * DD);
        ((float4*)&Vb[0][0])[tid]       = Vsrc[tid];
        ((float4*)&Vb[0][0])[256 + tid] = Vsrc[256 + tid];
        const int tv = tid >> 4, gk = tid & 15;
        *(float4*)&Kb[tv][gk * 4] = *(const float4*)(Kp + (rbase + tv) * DD + i0 + gk * 4);
    }

    // thread -> (i = i0 + w*8 + h, j = g*4..g*4+3); wave = 2 full rows per store
    const int g = tid & 31, h = tid >> 5;
    float4 acc[8];
    {   // init state from S0 (c==0) or chunk-end slice written by k_prefix
        const float* src = (c == 0) ? (S0 + (size_t)b * 16384)
                                    : (Sout + ((size_t)(b * TT) + c * CL - 1) * 16384);
        #pragma unroll
        for (int w = 0; w < 8; ++w)
            acc[w] = *(const float4*)(src + (size_t)(i0 + w * 8 + h) * DD + g * 4);
    }
    __syncthreads();

    float* sbase = Sout + rbase * 16384 + (size_t)i0 * DD + g * 4;
    for (int t = 0; t < CL - 1; ++t) {
        const float4 v4 = *(const float4*)&Vb[t][g * 4];
        #pragma unroll
        for (int w = 0; w < 8; ++w) {
            const float kk = Kb[t][w * 8 + h];
            acc[w].x += kk * v4.x; acc[w].y += kk * v4.y;
            acc[w].z += kk * v4.z; acc[w].w += kk * v4.w;
            *(float4*)(sbase + (size_t)t * 16384 + (size_t)(w * 8 + h) * DD) = acc[w];
        }
    }
}

// ---------------------------------------------------------------------------
extern "C" void kernel_launch(void* const* d_in, const int* in_sizes, int n_in,
                              void* d_out, int out_size, void* d_ws, size_t ws_size,
                              hipStream_t stream)
{
    const float* x  = (const float*)d_in[0];
    const float* S0 = (const float*)d_in[1];
    const float* Z0 = (const float*)d_in[2];
    const float* g  = (const float*)d_in[3];
    const float* be = (const float*)d_in[4];
    const float* Wk = (const float*)d_in[5];
    const float* Wq = (const float*)d_in[6];
    const float* Wv = (const float*)d_in[7];
    const float* W1 = (const float*)d_in[8];
    const float* b1 = (const float*)d_in[9];
    const float* W2 = (const float*)d_in[10];
    const float* b2 = (const float*)d_in[11];
    const float* Ws = (const float*)d_in[12];
    const float* bs = (const float*)d_in[13];

    float* outp = (float*)d_out;                    // [B,T,D]
    float* Sout = outp + (size_t)ROWS * DD;         // [B,T,D,D]
    float* Zout = Sout + (size_t)BB * TT * DD * DD; // [B,T,D]

    float* ws  = (float*)d_ws;
    float* Kp  = ws;
    float* Qp  = Kp + (size_t)ROWS * DD;
    float* Vp  = Qp + (size_t)ROWS * DD;
    float* XSp = Vp + (size_t)ROWS * DD;
    float* SKV = XSp + (size_t)ROWS * DD;
    float* SK  = SKV + (size_t)BB * NC * DD * DD;

    k_ln_qkv  <<<ROWS / 8, 256, 0, stream>>>(x, g, be, Wk, Wq, Wv, Ws, bs, Kp, Qp, Vp, XSp);
    k_chunksum<<<BB * NC, 256, 0, stream>>>(Kp, Vp, SKV, SK);
    k_prefix  <<<BB * DD * DD / 256, 256, 0, stream>>>(SKV, SK, S0, Z0, Sout, Zout);
    // num/mlp before the S-writer: chunk-end rows still L3-hot from k_prefix
    k_num_mlp <<<BB * NC, 256, 0, stream>>>(Qp, Kp, Vp, XSp, S0, Z0,
                                            W1, b1, W2, b2, Sout, Zout, outp);
    k_scan    <<<BB * NC * 2, 256, 0, stream>>>(Kp, Vp, S0, Sout);
}

// Round 3
// 384.699 us; speedup vs baseline: 1.0164x; 1.0164x over previous
//
#include <hip/hip_runtime.h>
#include <math.h>

#define BB 4
#define TT 1024
#define FIN 256
#define DD 128
#define CL 16              // chunk length
#define NC 64              // chunks = TT/CL
#define ROWS (BB*TT)       // 4096

typedef float f32x4_t __attribute__((ext_vector_type(4)));

static __device__ __forceinline__ void nt_store4(float* p, float4 v) {
    f32x4_t t; t.x = v.x; t.y = v.y; t.z = v.z; t.w = v.w;
    __builtin_nontemporal_store(t, (f32x4_t*)p);
}

// ---------------------------------------------------------------------------
// Kernel 1: LayerNorm + 4 GEMMs + per-chunk sums, fused.
// block = one chunk (16 rows). grid 256 x 256 threads.
//   - LN: 16 threads/row, 16 elems/thread
//   - GEMM: thread owns column d of {K or Q} and {V or XS} for all 16 rows
//   - threads 0..127 hold K col d AND V col d in registers -> SKV/SK in-block
// ---------------------------------------------------------------------------
__global__ __launch_bounds__(256) void k_ln_qkv_cs(
    const float* __restrict__ x, const float* __restrict__ gamma, const float* __restrict__ beta,
    const float* __restrict__ Wk, const float* __restrict__ Wq, const float* __restrict__ Wv,
    const float* __restrict__ Ws, const float* __restrict__ bs,
    float* __restrict__ Kp, float* __restrict__ Qp, float* __restrict__ Vp, float* __restrict__ XSp,
    float* __restrict__ SKV, float* __restrict__ SK)
{
    __shared__ float xt[CL][FIN];     // 16 KB
    __shared__ float Kb[CL][DD];      // 8 KB
    __shared__ float Vb[CL][DD];      // 8 KB
    const int tid  = threadIdx.x;
    const int c    = blockIdx.x & (NC - 1);
    const int b    = blockIdx.x >> 6;
    const int row0 = (b * TT + c * CL);

    // ---- LayerNorm: 16 threads per row, 16 elements per thread ----
    {
        const int r = tid >> 4, l = tid & 15;
        const float* xr = x + (size_t)(row0 + r) * FIN + l * 16;
        float v[16];
        #pragma unroll
        for (int k = 0; k < 16; ++k) v[k] = xr[k];
        float s = 0.f, sq = 0.f;
        #pragma unroll
        for (int k = 0; k < 16; ++k) { s += v[k]; sq += v[k] * v[k]; }
        #pragma unroll
        for (int m = 8; m >= 1; m >>= 1) {
            s  += __shfl_xor(s,  m, 64);
            sq += __shfl_xor(sq, m, 64);
        }
        const float mu  = s * (1.0f / FIN);
        const float var = sq * (1.0f / FIN) - mu * mu;
        const float rs  = rsqrtf(var + 1e-5f);
        #pragma unroll
        for (int k = 0; k < 16; ++k) {
            const int f = l * 16 + k;
            xt[r][f] = (v[k] - mu) * rs * gamma[f] + beta[f];
        }
    }
    __syncthreads();

    // ---- GEMM: thread -> 2 output columns across 16 rows ----
    const int m0 = tid >> 7;            // 0 -> K, 1 -> Q
    const int d  = tid & 127;
    const int m1 = (tid + 256) >> 7;    // 2 -> V, 3 -> XS
    const float* W0  = (m0 == 0 ? Wk : Wq) + (size_t)d * FIN;
    const float* W1r = (m1 == 2 ? Wv : Ws) + (size_t)d * FIN;

    float acc0[CL], acc1[CL];
    #pragma unroll
    for (int r = 0; r < CL; ++r) { acc0[r] = 0.f; acc1[r] = 0.f; }

    for (int k4 = 0; k4 < FIN / 4; ++k4) {
        const float4 w0 = ((const float4*)W0)[k4];
        const float4 w1 = ((const float4*)W1r)[k4];
        #pragma unroll
        for (int r = 0; r < CL; ++r) {
            const float4 xv = ((const float4*)xt[r])[k4];
            acc0[r] += w0.x * xv.x + w0.y * xv.y + w0.z * xv.z + w0.w * xv.w;
            acc1[r] += w1.x * xv.x + w1.y * xv.y + w1.z * xv.z + w1.w * xv.w;
        }
    }

    float* dst0 = (m0 == 0 ? Kp : Qp);
    float* dst1 = (m1 == 2 ? Vp : XSp);
    const float bsv = (m1 == 3) ? bs[d] : 0.f;
    #pragma unroll
    for (int r = 0; r < CL; ++r) {
        float a = acc0[r];
        a = (a > 0.f) ? (a + 1.f) : expf(a);          // phi = elu+1
        acc0[r] = a;
        dst0[(size_t)(row0 + r) * DD + d] = a;
        const float vv = acc1[r] + bsv;
        dst1[(size_t)(row0 + r) * DD + d] = vv;
        if (m0 == 0) {                  // tid < 128: owns K col d and V col d
            Kb[r][d] = a;
            Vb[r][d] = vv;
        }
    }

    // SK straight from registers (threads 0..127 hold phi(K) col d)
    if (m0 == 0) {
        float s = 0.f;
        #pragma unroll
        for (int r = 0; r < CL; ++r) s += acc0[r];
        SK[(size_t)(b * NC + c) * DD + d] = s;
    }
    __syncthreads();

    // ---- per-chunk sumKV[i][j] = sum_t K[t,i] V[t,j] ----
    {
        const int j = tid & 127, hi = tid >> 7;
        float acc[64];
        #pragma unroll
        for (int w = 0; w < 64; ++w) acc[w] = 0.f;

        for (int t = 0; t < CL; ++t) {
            const float vj = Vb[t][j];
            #pragma unroll
            for (int w4 = 0; w4 < 16; ++w4) {
                const float4 kf = *(const float4*)&Kb[t][hi * 64 + w4 * 4];
                acc[w4 * 4 + 0] += kf.x * vj;
                acc[w4 * 4 + 1] += kf.y * vj;
                acc[w4 * 4 + 2] += kf.z * vj;
                acc[w4 * 4 + 3] += kf.w * vj;
            }
        }
        float* out = SKV + (size_t)(b * NC + c) * DD * DD;
        #pragma unroll
        for (int w = 0; w < 64; ++w) {
            const int i = hi * 64 + w;
            out[(size_t)i * DD + j] = acc[w];
        }
    }
}

// ---------------------------------------------------------------------------
// Kernel 2: prefix over chunks -> writes chunk-END slices of S and Z outputs.
// Loads batched 8-wide for ILP. grid 256 x 256 (one thread per (b,i,j))
// ---------------------------------------------------------------------------
__global__ __launch_bounds__(256) void k_prefix(
    const float* __restrict__ SKV, const float* __restrict__ SK,
    const float* __restrict__ S0, const float* __restrict__ Z0,
    float* __restrict__ Sout, float* __restrict__ Zout)
{
    const int gid = blockIdx.x * 256 + threadIdx.x;   // 0..65535
    const int b = gid >> 14, e = gid & 16383;
    float acc = S0[(size_t)b * 16384 + e];
    const float* p = SKV + (size_t)b * NC * 16384 + e;
    float* so = Sout + (size_t)b * TT * 16384 + (size_t)(CL - 1) * 16384 + e;
    for (int c0 = 0; c0 < NC; c0 += 8) {
        float v[8];
        #pragma unroll
        for (int q = 0; q < 8; ++q) v[q] = p[(size_t)(c0 + q) * 16384];
        #pragma unroll
        for (int q = 0; q < 8; ++q) { acc += v[q]; so[(size_t)(c0 + q) * CL * 16384] = acc; }
    }
    if (gid < BB * DD) {
        const int b2 = gid >> 7, i = gid & 127;
        float z = Z0[b2 * DD + i];
        const float* pk = SK + (size_t)b2 * NC * DD + i;
        float* zo = Zout + ((size_t)b2 * TT + CL - 1) * DD + i;
        for (int c0 = 0; c0 < NC; c0 += 8) {
            float v[8];
            #pragma unroll
            for (int q = 0; q < 8; ++q) v[q] = pk[(size_t)(c0 + q) * DD];
            #pragma unroll
            for (int q = 0; q < 8; ++q) { z += v[q]; zo[(size_t)(c0 + q) * CL * DD] = z; }
        }
    }
}

// ---------------------------------------------------------------------------
// Kernel 3: fused NUM/den/MLP via chunked-linear-attention identity.
//   A = mask(Q K^T); num[t] = Q[t]@S_start + sum_u A[t,u] V[u]
//   den[t] = Q[t].Z_start + rowsum(A[t]);  h0 = num/den -> MLP -> + XS
// Also writes Z rows t<CL-1. grid 256 (b*c) x 256 threads.
// ---------------------------------------------------------------------------
__global__ __launch_bounds__(256) void k_num_mlp(
    const float* __restrict__ Qp, const float* __restrict__ Kp, const float* __restrict__ Vp,
    const float* __restrict__ XSp, const float* __restrict__ S0, const float* __restrict__ Z0,
    const float* __restrict__ W1, const float* __restrict__ b1,
    const float* __restrict__ W2, const float* __restrict__ b2,
    const float* Sce,            // = Sout (reads chunk-end rows only)
    float* Zout,                 // reads chunk-end rows, writes rows t<CL-1
    float* __restrict__ Oout)
{
    __shared__ float Qb[CL][132];
    __shared__ float Kb[CL][132];
    __shared__ float Vb[CL][DD];
    __shared__ float Ab[CL][CL];
    __shared__ float zs[DD];
    __shared__ float red[2][CL][DD];
    __shared__ float h0[CL][DD];
    __shared__ float h1[CL][DD];
    __shared__ float parr[CL][256];
    __shared__ float denl[CL];

    const int tid = threadIdx.x;
    const int c = blockIdx.x & (NC - 1);
    const int b = blockIdx.x >> 6;
    const size_t rbase = (size_t)(b * TT + c * CL);
    const int d = tid & 127, s = tid >> 7;

    float4 w1r[16], w2r[16];
    #pragma unroll
    for (int k4 = 0; k4 < 16; ++k4) {
        w1r[k4] = *(const float4*)(W1 + (size_t)d * DD + s * 64 + k4 * 4);
        w2r[k4] = *(const float4*)(W2 + (size_t)d * DD + s * 64 + k4 * 4);
    }

    #pragma unroll
    for (int q = 0; q < 2; ++q) {
        const int idx = q * 256 + tid;
        const int t = idx >> 5, jq = idx & 31;
        *(float4*)&Qb[t][jq * 4] = *(const float4*)(Qp + (rbase + t) * DD + jq * 4);
        *(float4*)&Kb[t][jq * 4] = *(const float4*)(Kp + (rbase + t) * DD + jq * 4);
        ((float4*)&Vb[0][0])[idx] = ((const float4*)(Vp + rbase * DD))[idx];
    }
    if (tid < DD)
        zs[tid] = (c == 0) ? Z0[b * DD + tid] : Zout[(rbase - 1) * DD + tid];
    __syncthreads();

    {   // A = mask(QK^T), den
        const int t = tid >> 4, u = tid & 15;
        float a = 0.f;
        #pragma unroll
        for (int k4 = 0; k4 < 32; ++k4) {
            const float4 q4 = *(const float4*)&Qb[t][k4 * 4];
            const float4 kv = *(const float4*)&Kb[u][k4 * 4];
            a += q4.x * kv.x + q4.y * kv.y + q4.z * kv.z + q4.w * kv.w;
        }
        const float am = (u <= t) ? a : 0.f;
        Ab[t][u] = am;
        float dz = 0.f;
        #pragma unroll
        for (int kk = 0; kk < 8; ++kk) dz += Qb[t][u * 8 + kk] * zs[u * 8 + kk];
        float r = am + dz;
        #pragma unroll
        for (int m = 1; m <= 8; m <<= 1) r += __shfl_xor(r, m, 64);
        if (u == 0) denl[t] = r + 1e-5f;
    }

    if (tid < DD) {   // Z rows t < CL-1
        float z = zs[tid];
        for (int t = 0; t < CL - 1; ++t) {
            z += Kb[t][tid];
            Zout[(rbase + t) * DD + tid] = z;
        }
    }
    __syncthreads();

    {   // NUM part1: Q @ S_start (k split across s halves)
        float nt[CL];
        #pragma unroll
        for (int t = 0; t < CL; ++t) nt[t] = 0.f;
        const float* sst = (c == 0) ? (S0 + (size_t)b * 16384)
                                    : (Sce + (rbase - 1) * 16384);
        #pragma unroll 4
        for (int k4 = s * 16; k4 < s * 16 + 16; ++k4) {
            const int k = k4 * 4;
            const float sv0 = sst[(size_t)(k + 0) * DD + d];
            const float sv1 = sst[(size_t)(k + 1) * DD + d];
            const float sv2 = sst[(size_t)(k + 2) * DD + d];
            const float sv3 = sst[(size_t)(k + 3) * DD + d];
            #pragma unroll
            for (int t = 0; t < CL; ++t) {
                const float4 q4 = *(const float4*)&Qb[t][k];
                nt[t] += q4.x * sv0 + q4.y * sv1 + q4.z * sv2 + q4.w * sv3;
            }
        }
        #pragma unroll
        for (int t = 0; t < CL; ++t) red[s][t][d] = nt[t];
    }
    __syncthreads();

    #pragma unroll
    for (int tl = 0; tl < 8; ++tl) {    // num += A@V, h0 = num/den
        const int t = s * 8 + tl;
        float num = red[0][t][d] + red[1][t][d];
        #pragma unroll
        for (int u = 0; u < CL; ++u) num += Ab[t][u] * Vb[u][d];
        h0[t][d] = num / denl[t];
    }
    __syncthreads();

    #pragma unroll
    for (int r = 0; r < 16; ++r) {      // MLP layer 1
        float pp = 0.f;
        #pragma unroll
        for (int k4 = 0; k4 < 16; ++k4) {
            const float4 xv = *(const float4*)&h0[r][s * 64 + k4 * 4];
            pp += w1r[k4].x * xv.x + w1r[k4].y * xv.y + w1r[k4].z * xv.z + w1r[k4].w * xv.w;
        }
        parr[r][tid] = pp;
    }
    __syncthreads();
    #pragma unroll
    for (int q = 0; q < 8; ++q) {
        const int f = q * 256 + tid;
        const int r = f >> 7, dd2 = f & 127;
        h1[r][dd2] = fmaxf(parr[r][dd2] + parr[r][dd2 + 128] + b1[dd2], 0.f);
    }
    __syncthreads();

    #pragma unroll
    for (int r = 0; r < 16; ++r) {      // MLP layer 2
        float pp = 0.f;
        #pragma unroll
        for (int k4 = 0; k4 < 16; ++k4) {
            const float4 xv = *(const float4*)&h1[r][s * 64 + k4 * 4];
            pp += w2r[k4].x * xv.x + w2r[k4].y * xv.y + w2r[k4].z * xv.z + w2r[k4].w * xv.w;
        }
        parr[r][tid] = pp;
    }
    __syncthreads();
    #pragma unroll
    for (int q = 0; q < 8; ++q) {
        const int f = q * 256 + tid;
        const int r = f >> 7, dd2 = f & 127;
        const float hv = fmaxf(parr[r][dd2] + parr[r][dd2 + 128] + b2[dd2], 0.f);
        Oout[rbase * DD + f] = hv + XSp[rbase * DD + f];
    }
}

// ---------------------------------------------------------------------------
// Kernel 4: pure S-row writer, 4-way i-split. block = (b, chunk, i-quarter).
// State 32x128 in registers (16 floats/thread). No barriers in the t-loop.
// Wave store = 1 KB fully-contiguous; stores are NON-TEMPORAL (S never
// re-read; keep the 251 MB stream out of L2). grid 1024 x 256 threads.
// ---------------------------------------------------------------------------
__global__ __launch_bounds__(256) void k_scan(
    const float* __restrict__ Kp, const float* __restrict__ Vp,
    const float* __restrict__ S0, float* Sout)
{
    __shared__ float Kb[CL][32];
    __shared__ float Vb[CL][DD];
    const int tid = threadIdx.x;
    const int ih  = blockIdx.x & 3;
    const int c   = (blockIdx.x >> 2) & (NC - 1);
    const int b   = blockIdx.x >> 8;
    const int i0  = ih * 32;
    const size_t rbase = (size_t)(b * TT + c * CL);

    {   // stage V (full) + K slice for this i-quarter
        const float4* Vsrc = (const float4*)(Vp + rbase * DD);
        ((float4*)&Vb[0][0])[tid]       = Vsrc[tid];
        ((float4*)&Vb[0][0])[256 + tid] = Vsrc[256 + tid];
        if (tid < 128) {
            const int tv = tid >> 3, gk = tid & 7;
            *(float4*)&Kb[tv][gk * 4] = *(const float4*)(Kp + (rbase + tv) * DD + i0 + gk * 4);
        }
    }

    // thread -> (i = i0 + w*8 + h, j = g*4..g*4+3); wave = 2 adjacent rows/store
    const int g = tid & 31, h = tid >> 5;
    float4 acc[4];
    {   // init from S0 (c==0) or chunk-end slice written by k_prefix
        const float* src = (c == 0) ? (S0 + (size_t)b * 16384)
                                    : (Sout + ((size_t)(b * TT) + c * CL - 1) * 16384);
        #pragma unroll
        for (int w = 0; w < 4; ++w)
            acc[w] = *(const float4*)(src + (size_t)(i0 + w * 8 + h) * DD + g * 4);
    }
    __syncthreads();

    float* sbase = Sout + rbase * 16384 + (size_t)i0 * DD + g * 4;
    for (int t = 0; t < CL - 1; ++t) {
        const float4 v4 = *(const float4*)&Vb[t][g * 4];
        #pragma unroll
        for (int w = 0; w < 4; ++w) {
            const float kk = Kb[t][w * 8 + h];
            acc[w].x += kk * v4.x; acc[w].y += kk * v4.y;
            acc[w].z += kk * v4.z; acc[w].w += kk * v4.w;
            nt_store4(sbase + (size_t)t * 16384 + (size_t)(w * 8 + h) * DD, acc[w]);
        }
    }
}

// ---------------------------------------------------------------------------
extern "C" void kernel_launch(void* const* d_in, const int* in_sizes, int n_in,
                              void* d_out, int out_size, void* d_ws, size_t ws_size,
                              hipStream_t stream)
{
    const float* x  = (const float*)d_in[0];
    const float* S0 = (const float*)d_in[1];
    const float* Z0 = (const float*)d_in[2];
    const float* g  = (const float*)d_in[3];
    const float* be = (const float*)d_in[4];
    const float* Wk = (const float*)d_in[5];
    const float* Wq = (const float*)d_in[6];
    const float* Wv = (const float*)d_in[7];
    const float* W1 = (const float*)d_in[8];
    const float* b1 = (const float*)d_in[9];
    const float* W2 = (const float*)d_in[10];
    const float* b2 = (const float*)d_in[11];
    const float* Ws = (const float*)d_in[12];
    const float* bs = (const float*)d_in[13];

    float* outp = (float*)d_out;                    // [B,T,D]
    float* Sout = outp + (size_t)ROWS * DD;         // [B,T,D,D]
    float* Zout = Sout + (size_t)BB * TT * DD * DD; // [B,T,D]

    float* ws  = (float*)d_ws;
    float* Kp  = ws;
    float* Qp  = Kp + (size_t)ROWS * DD;
    float* Vp  = Qp + (size_t)ROWS * DD;
    float* XSp = Vp + (size_t)ROWS * DD;
    float* SKV = XSp + (size_t)ROWS * DD;
    float* SK  = SKV + (size_t)BB * NC * DD * DD;

    k_ln_qkv_cs<<<BB * NC, 256, 0, stream>>>(x, g, be, Wk, Wq, Wv, Ws, bs,
                                             Kp, Qp, Vp, XSp, SKV, SK);
    k_prefix   <<<BB * DD * DD / 256, 256, 0, stream>>>(SKV, SK, S0, Z0, Sout, Zout);
    // num/mlp before the S-writer: chunk-end rows still L3-hot from k_prefix
    k_num_mlp  <<<BB * NC, 256, 0, stream>>>(Qp, Kp, Vp, XSp, S0, Z0,
                                             W1, b1, W2, b2, Sout, Zout, outp);
    k_scan     <<<BB * NC * 4, 256, 0, stream>>>(Kp, Vp, S0, Sout);
}